// Round 12
// baseline (217.068 us; speedup 1.0000x reference)
//
#include <hip/hip_runtime.h>
#include <hip/hip_bf16.h>

typedef float  f32x2  __attribute__((ext_vector_type(2)));
typedef float  f32x4  __attribute__((ext_vector_type(4)));
typedef float  f32x16 __attribute__((ext_vector_type(16)));
typedef __bf16 bf16x8 __attribute__((ext_vector_type(8)));

#define MFMA16(A,B,C) __builtin_amdgcn_mfma_f32_16x16x32_bf16((A),(B),(C),0,0,0)
#define MFMA32(A,B,C) __builtin_amdgcn_mfma_f32_32x32x16_bf16((A),(B),(C),0,0,0)
#define EXP2(x) __builtin_amdgcn_exp2f(x)
#define LOG2(x) __builtin_amdgcn_logf(x)

static constexpr int Tn = 2048, Bn = 2, En = 1024, Hn = 16, Dn = 64;
// Q is pre-scaled by (1/sqrt(D)) * log2(e): all score math is in log2 domain.
static constexpr float kQScale = 0.125f * 1.4426950408889634f;

static __device__ __forceinline__ unsigned pack2(float a, float b) {
  union { __bf16 h[2]; unsigned u; } un;
  un.h[0] = (__bf16)a; un.h[1] = (__bf16)b;
  return un.u;
}

// async global->LDS, 16B per lane; LDS dest is wave-uniform base + lane*16
static __device__ __forceinline__ void gload_lds16(const void* g, void* l) {
  __builtin_amdgcn_global_load_lds(
      (const __attribute__((address_space(1))) void*)g,
      (__attribute__((address_space(3))) void*)l, 16, 0, 0);
}

// ---------------------------------------------------------------------------
// Kernel 0: fp32 -> bf16 convert of the two weight matrices only (~17 MB).
// X inputs are consumed fp32 directly by k_qkv (converted in-register).
// ---------------------------------------------------------------------------
__global__ __launch_bounds__(256)
void k_cvtw(const float* __restrict__ w3, const float* __restrict__ wo,
            __bf16* __restrict__ w3b, __bf16* __restrict__ wob)
{
  const size_t g = (size_t)blockIdx.x * 256 + threadIdx.x;  // granule id
  const float* src;
  __bf16* dst;
  size_t off;
  if (g < 393216) { src = w3; dst = w3b; off = g; }
  else            { src = wo; dst = wob; off = g - 393216; }
  const float* p = src + off * 8;
  f32x4 a = *reinterpret_cast<const f32x4*>(p);
  f32x4 b = *reinterpret_cast<const f32x4*>(p + 4);
  bf16x8 o;
  #pragma unroll
  for (int e = 0; e < 4; ++e) { o[e] = (__bf16)a[e]; o[e + 4] = (__bf16)b[e]; }
  *reinterpret_cast<bf16x8*>(dst + off * 8) = o;
}

// ---------------------------------------------------------------------------
// Kernel 1: fused QKV in-projection. A = fp32 X, reg-staged + converted to
// bf16 at ds_write (LDS layout = proven bf16 [4 kg][128 r][16B]); B = bf16
// weights via global_load_lds. 2-buffer prefetch, 1 barrier/K-step.
// V-slice (which==2) writes DIRECTLY in V^T [bh][d][t] layout.
// ---------------------------------------------------------------------------
__global__ __launch_bounds__(256)
void k_qkv(const float* __restrict__ Xq, const float* __restrict__ Xk,
           const float* __restrict__ Xv, const __bf16* __restrict__ W,
           const float* __restrict__ bias,
           __bf16* __restrict__ q_ws, __bf16* __restrict__ k_ws,
           __bf16* __restrict__ vt_ws)
{
  __shared__ __align__(16) char a_lds[2][8192];
  __shared__ __align__(16) char b_lds[2][8192];
  const int tid = threadIdx.x;
  const int lane = tid & 63, w = tid >> 6;
  const int wr = w >> 1, wc = w & 1;
  const int ag = lane >> 4, lr = lane & 15;
  const int mBase = blockIdx.x * 128;
  const int oBase = blockIdx.y * 128;
  const int which = blockIdx.y >> 3;
  const float* X = (which == 0) ? Xq : ((which == 1) ? Xk : Xv);
  const __bf16* Wt = W + (size_t)oBase * En;
  const float oscale = (which == 0) ? kQScale : 1.0f;

  const int gA = w;                             // wave owns k-granule w
  const float* pxa0 = X + (size_t)(mBase + lane) * En + gA * 8;
  const float* pxa1 = X + (size_t)(mBase + 64 + lane) * En + gA * 8;
  const __bf16* pb0 = Wt + (size_t)lane * En + gA * 8;
  const __bf16* pb1 = Wt + (size_t)(64 + lane) * En + gA * 8;
  const int dA0 = gA * 2048 + lane * 16;        // ds_write addrs (linear)
  const int dA1 = gA * 2048 + 1024 + lane * 16;

  f32x4 a0lo, a0hi, a1lo, a1hi;                 // fp32 A stage regs

#define ALOAD(KK) do {                                                       \
    a0lo = *(const f32x4*)(pxa0 + (KK));                                     \
    a0hi = *(const f32x4*)(pxa0 + (KK) + 4);                                 \
    a1lo = *(const f32x4*)(pxa1 + (KK));                                     \
    a1hi = *(const f32x4*)(pxa1 + (KK) + 4);                                 \
  } while (0)
#define AWRITE(BUF) do {                                                     \
    bf16x8 v0, v1;                                                           \
    _Pragma("unroll")                                                        \
    for (int e = 0; e < 4; ++e) {                                            \
      v0[e] = (__bf16)a0lo[e]; v0[e + 4] = (__bf16)a0hi[e];                  \
      v1[e] = (__bf16)a1lo[e]; v1[e + 4] = (__bf16)a1hi[e];                  \
    }                                                                        \
    *(bf16x8*)(&a_lds[(BUF)][dA0]) = v0;                                     \
    *(bf16x8*)(&a_lds[(BUF)][dA1]) = v1;                                     \
  } while (0)

  f32x4 acc[4][4];
  #pragma unroll
  for (int i = 0; i < 4; ++i)
    #pragma unroll
    for (int j = 0; j < 4; ++j) { f32x4 z = {0.f, 0.f, 0.f, 0.f}; acc[i][j] = z; }

  // prologue: tile 0
  ALOAD(0);
  AWRITE(0);
  gload_lds16(pb0, &b_lds[0][gA * 2048]);
  gload_lds16(pb1, &b_lds[0][gA * 2048 + 1024]);
  __syncthreads();

  for (int kt = 0; kt < 32; ++kt) {
    const int cur = kt & 1, nxt = cur ^ 1;
    if (kt + 1 < 32) {                 // issue next tile's loads pre-compute
      const int kk = (kt + 1) * 32;
      ALOAD(kk);
      gload_lds16(pb0 + kk, &b_lds[nxt][gA * 2048]);
      gload_lds16(pb1 + kk, &b_lds[nxt][gA * 2048 + 1024]);
    }
    bf16x8 af[4], bfr[4];
    #pragma unroll
    for (int mb = 0; mb < 4; ++mb)
      af[mb] = *(const bf16x8*)(&a_lds[cur][ag * 2048 + (wr * 64 + mb * 16 + lr) * 16]);
    #pragma unroll
    for (int nb = 0; nb < 4; ++nb)
      bfr[nb] = *(const bf16x8*)(&b_lds[cur][ag * 2048 + (wc * 64 + nb * 16 + lr) * 16]);
    #pragma unroll
    for (int mb = 0; mb < 4; ++mb)
      #pragma unroll
      for (int nb = 0; nb < 4; ++nb)
        acc[mb][nb] = MFMA16(af[mb], bfr[nb], acc[mb][nb]);
    if (kt + 1 < 32) AWRITE(nxt);      // regs landed during compute (T14)
    __syncthreads();                   // drains gll B + lgkm
  }
#undef ALOAD
#undef AWRITE

  __bf16* dqk = (which == 0) ? q_ws : k_ws;
  #pragma unroll
  for (int nb = 0; nb < 4; ++nb) {
    int oG = oBase + wc * 64 + nb * 16 + lr;
    float bv = bias[oG];
    int oS = oG & (En - 1);
    int h = oS >> 6, d = oS & 63;
    #pragma unroll
    for (int mb = 0; mb < 4; ++mb)
      #pragma unroll
      for (int r = 0; r < 4; ++r) {
        int i = mBase + wr * 64 + mb * 16 + ag * 4 + r;
        int t = i >> 1, b2 = i & 1;
        __bf16 val = (__bf16)((acc[mb][nb][r] + bv) * oscale);
        if (which == 2)
          vt_ws[(((size_t)(b2 * Hn + h)) * Dn + d) * Tn + t] = val;
        else
          dqk[(((size_t)(b2 * Hn + h)) * Tn + t) * Dn + d] = val;
      }
  }
}

// ---------------------------------------------------------------------------
// Kernel 2: flash attention (R6-proven 64 µs structure, verbatim).
// Swapped 32x32 MFMA, log2 domain, l via MFMA-vs-ones, permlane32_swap
// P-transpose, defer-max, dbuf K/V (1 barrier/iter), setprio.
// ---------------------------------------------------------------------------
__global__ __launch_bounds__(256, 2)
void k_flash(const __bf16* __restrict__ q_ws, const __bf16* __restrict__ k_ws,
             const __bf16* __restrict__ vt_ws, __bf16* __restrict__ ctx,
             float* __restrict__ adj_g)
{
  __shared__ __align__(16) char kv_sm[2 * 16384];  // [buf][K 8KB | V 8KB]

  const int tid = threadIdx.x;
  const int lane = tid & 63, w = tid >> 6;
  const int tl = lane & 31, hi = lane >> 5;
  const int bh = blockIdx.x >> 4;
  const int qt = blockIdx.x & 15;
  const int t0w = qt * 128 + w * 32;

  const __bf16* kbase  = k_ws + (size_t)bh * Tn * Dn;
  const __bf16* vtbase = vt_ws + (size_t)bh * Dn * Tn;

  bf16x8 qf[4];
  {
    const __bf16* qrow = q_ws + ((size_t)bh * Tn + t0w + tl) * Dn + hi * 8;
    #pragma unroll
    for (int c = 0; c < 4; ++c)
      qf[c] = *reinterpret_cast<const bf16x8*>(qrow + c * 16);
  }

  union { unsigned u[4]; bf16x8 v; } onu;
  #pragma unroll
  for (int j = 0; j < 4; ++j) onu.u[j] = 0x3F803F80u;
  const bf16x8 kOne = onu.v;

  f32x16 accO0, accO1, accL;
  #pragma unroll
  for (int i = 0; i < 16; ++i) { accO0[i] = 0.f; accO1[i] = 0.f; accL[i] = 0.f; }
  float m_run = -INFINITY;

  const int r0 = tid >> 3, s0 = tid & 7;
  const int ldso = ((s0 ^ (r0 & 7)) << 4);
  const int ko0 = r0 * 128 + ldso;              // +4096 => rows 32..63

  bf16x8 rk0 = *(const bf16x8*)(kbase + r0 * 64 + s0 * 8);
  bf16x8 rk1 = *(const bf16x8*)(kbase + (r0 + 32) * 64 + s0 * 8);
  bf16x8 rv0 = *(const bf16x8*)(vtbase + (size_t)r0 * Tn + s0 * 8);
  bf16x8 rv1 = *(const bf16x8*)(vtbase + (size_t)(r0 + 32) * Tn + s0 * 8);
  *(bf16x8*)(kv_sm + ko0) = rk0;
  *(bf16x8*)(kv_sm + ko0 + 4096) = rk1;
  *(bf16x8*)(kv_sm + 8192 + ko0) = rv0;
  *(bf16x8*)(kv_sm + 8192 + ko0 + 4096) = rv1;

  for (int st = 0; st < 32; ++st) {
    __syncthreads();
    const char* cur = kv_sm + (st & 1) * 16384;
    char* nxt = kv_sm + ((st + 1) & 1) * 16384;
    if (st + 1 < 32) {   // issue next tile's loads; land during compute (T14)
      const __bf16* kn = kbase + (size_t)(st + 1) * 64 * Dn;
      const __bf16* vn = vtbase + (st + 1) * 64;
      rk0 = *(const bf16x8*)(kn + r0 * 64 + s0 * 8);
      rk1 = *(const bf16x8*)(kn + (r0 + 32) * 64 + s0 * 8);
      rv0 = *(const bf16x8*)(vn + (size_t)r0 * Tn + s0 * 8);
      rv1 = *(const bf16x8*)(vn + (size_t)(r0 + 32) * Tn + s0 * 8);
    }

    f32x16 sc0, sc1;
    #pragma unroll
    for (int i = 0; i < 16; ++i) { sc0[i] = 0.f; sc1[i] = 0.f; }
    const char* kr0 = cur + tl * 128;
    const char* kr1 = cur + (32 + tl) * 128;
    __builtin_amdgcn_s_setprio(1);
    #pragma unroll
    for (int c = 0; c < 4; ++c) {
      const int off = (((2 * c + hi) ^ (tl & 7)) << 4);
      sc0 = MFMA32(*(const bf16x8*)(kr0 + off), qf[c], sc0);
      sc1 = MFMA32(*(const bf16x8*)(kr1 + off), qf[c], sc1);
    }
    __builtin_amdgcn_s_setprio(0);

    float mx[8];
    #pragma unroll
    for (int i = 0; i < 8; ++i)
      mx[i] = fmaxf(fmaxf(sc0[i], sc0[i + 8]), fmaxf(sc1[i], sc1[i + 8]));
    float tm = fmaxf(fmaxf(fmaxf(mx[0], mx[1]), fmaxf(mx[2], mx[3])),
                     fmaxf(fmaxf(mx[4], mx[5]), fmaxf(mx[6], mx[7])));
    tm = fmaxf(tm, __shfl_xor(tm, 32, 64));
    if (__any(tm > m_run + 8.0f)) {
      const float mn = fmaxf(m_run, tm);
      const float es = EXP2(m_run - mn);   // 0 on first tile
      m_run = mn;
      #pragma unroll
      for (int q = 0; q < 4; ++q)
        #pragma unroll
        for (int rr = 0; rr < 4; ++rr) {
          const float e = __shfl(es, 8 * q + 4 * hi + rr, 32);
          accO0[q * 4 + rr] *= e;
          accO1[q * 4 + rr] *= e;
          accL[q * 4 + rr] *= e;
        }
    }
    #pragma unroll
    for (int i = 0; i < 16; ++i) {
      sc0[i] = EXP2(sc0[i] - m_run);
      sc1[i] = EXP2(sc1[i] - m_run);
    }

    unsigned wA0[4], wB0[4], wA1[4], wB1[4];
    #pragma unroll
    for (int g = 0; g < 4; ++g) {
      wA0[g] = pack2(sc0[4 * g],     sc0[4 * g + 1]);
      wB0[g] = pack2(sc0[4 * g + 2], sc0[4 * g + 3]);
      wA1[g] = pack2(sc1[4 * g],     sc1[4 * g + 1]);
      wB1[g] = pack2(sc1[4 * g + 2], sc1[4 * g + 3]);
    }
    bf16x8 pa[2][2];
    #pragma unroll
    for (int sb = 0; sb < 2; ++sb) {
      const unsigned* WA = sb ? wA1 : wA0;
      const unsigned* WB = sb ? wB1 : wB0;
      #pragma unroll
      for (int c = 0; c < 2; ++c) {
        unsigned w0 = WA[2 * c], w2 = WA[2 * c + 1];
        unsigned w1 = WB[2 * c], w3 = WB[2 * c + 1];
        asm("v_permlane32_swap_b32 %0, %1" : "+v"(w0), "+v"(w2));
        asm("v_permlane32_swap_b32 %0, %1" : "+v"(w1), "+v"(w3));
        union { unsigned u[4]; bf16x8 v; } uu;
        uu.u[0] = w0; uu.u[1] = w1; uu.u[2] = w2; uu.u[3] = w3;
        pa[sb][c] = uu.v;
      }
    }

    const char* vr0 = cur + 8192 + tl * 128;
    const char* vr1 = cur + 8192 + (32 + tl) * 128;
    __builtin_amdgcn_s_setprio(1);
    #pragma unroll
    for (int sb = 0; sb < 2; ++sb)
      #pragma unroll
      for (int c = 0; c < 2; ++c) {
        const int off = (((sb * 4 + c * 2 + hi) ^ (tl & 7)) << 4);
        accO0 = MFMA32(pa[sb][c], *(const bf16x8*)(vr0 + off), accO0);
        accO1 = MFMA32(pa[sb][c], *(const bf16x8*)(vr1 + off), accO1);
        accL  = MFMA32(pa[sb][c], kOne, accL);
      }
    __builtin_amdgcn_s_setprio(0);

    if (st + 1 < 32) {
      *(bf16x8*)(nxt + ko0) = rk0;
      *(bf16x8*)(nxt + ko0 + 4096) = rk1;
      *(bf16x8*)(nxt + 8192 + ko0) = rv0;
      *(bf16x8*)(nxt + 8192 + ko0 + 4096) = rv1;
    }
  }

  const int b2 = bh >> 4, h = bh & 15;
  float adjv[16];
  #pragma unroll
  for (int q = 0; q < 4; ++q)
    #pragma unroll
    for (int rr = 0; rr < 4; ++rr) {
      const int j = q * 4 + rr;
      const float lv = 1.0f / accL[j];
      const int t = t0w + 8 * q + 4 * hi + rr;
      __bf16* cp = ctx + ((size_t)t * Bn + b2) * En + h * 64 + tl;
      cp[0]  = (__bf16)(accO0[j] * lv);
      cp[32] = (__bf16)(accO1[j] * lv);
      const float mrow = __shfl(m_run, 8 * q + 4 * hi + rr, 32);
      adjv[j] = mrow + LOG2(16.0f * accL[j]);
    }
  if (tl == 0) {
    #pragma unroll
    for (int q = 0; q < 4; ++q)
      #pragma unroll
      for (int rr = 0; rr < 4; ++rr) {
        const int t = t0w + 8 * q + 4 * hi + rr;
        adj_g[(size_t)bh * Tn + t] = adjv[q * 4 + rr];
      }
  }
}

// ---------------------------------------------------------------------------
// Kernel 3: avg attention weights (recompute QK^T; adj precomputed by flash).
// Double-buffered Q/K LDS, 1 barrier per head (R6-proven version).
// ---------------------------------------------------------------------------
__global__ __launch_bounds__(256)
void k_avgw(const __bf16* __restrict__ q_ws, const __bf16* __restrict__ k_ws,
            const float* __restrict__ adj_g, float* __restrict__ avg_out)
{
  __shared__ __align__(16) char q_sm[2][8192];
  __shared__ __align__(16) char k_sm[2][8192];
  __shared__ __align__(16) float adj_sm[16][64];

  const int tid = threadIdx.x;
  const int lane = tid & 63, w = tid >> 6;
  const int tl = lane & 31, hi = lane >> 5;
  const int b2 = blockIdx.x >> 10;
  const int tt = (blockIdx.x >> 5) & 31;
  const int ss = blockIdx.x & 31;
  const int thalf = (w >> 1) * 32, shalf = (w & 1) * 32;

  #pragma unroll
  for (int it = 0; it < 4; ++it) {
    int idx = tid + it * 256;
    int h = idx >> 6, trow = idx & 63;
    adj_sm[h][trow] = adj_g[((size_t)(b2 * Hn + h)) * Tn + tt * 64 + trow];
  }

  const size_t hstride = (size_t)Tn * Dn;
  const __bf16* qb = q_ws + ((size_t)(b2 * Hn) * Tn + tt * 64) * Dn;
  const __bf16* kb = k_ws + ((size_t)(b2 * Hn) * Tn + ss * 64) * Dn;

  const int r0 = tid >> 3, s0 = tid & 7;
  const int ldso = ((s0 ^ (r0 & 7)) << 4);
  const int ko0 = r0 * 128 + ldso;               // +4096 => rows 32..63

  bf16x8 rq0 = *(const bf16x8*)(qb + r0 * 64 + s0 * 8);
  bf16x8 rq1 = *(const bf16x8*)(qb + (r0 + 32) * 64 + s0 * 8);
  bf16x8 rk0 = *(const bf16x8*)(kb + r0 * 64 + s0 * 8);
  bf16x8 rk1 = *(const bf16x8*)(kb + (r0 + 32) * 64 + s0 * 8);
  *(bf16x8*)(q_sm[0] + ko0) = rq0;
  *(bf16x8*)(q_sm[0] + ko0 + 4096) = rq1;
  *(bf16x8*)(k_sm[0] + ko0) = rk0;
  *(bf16x8*)(k_sm[0] + ko0 + 4096) = rk1;

  f32x16 avg;
  #pragma unroll
  for (int i = 0; i < 16; ++i) avg[i] = 0.f;

  for (int h = 0; h < Hn; ++h) {
    __syncthreads();
    const char* qc = q_sm[h & 1];
    const char* kc = k_sm[h & 1];
    char* qn = q_sm[(h + 1) & 1];
    char* kn = k_sm[(h + 1) & 1];
    if (h + 1 < Hn) {
      const __bf16* qp = qb + (size_t)(h + 1) * hstride;
      const __bf16* kp2 = kb + (size_t)(h + 1) * hstride;
      rq0 = *(const bf16x8*)(qp + r0 * 64 + s0 * 8);
      rq1 = *(const bf16x8*)(qp + (r0 + 32) * 64 + s0 * 8);
      rk0 = *(const bf16x8*)(kp2 + r0 * 64 + s0 * 8);
      rk1 = *(const bf16x8*)(kp2 + (r0 + 32) * 64 + s0 * 8);
    }

    f32x16 sc;
    #pragma unroll
    for (int i = 0; i < 16; ++i) sc[i] = 0.f;
    const char* qr = qc + (thalf + tl) * 128;
    const char* kr = kc + (shalf + tl) * 128;
    #pragma unroll
    for (int c = 0; c < 4; ++c) {
      const int off = (((2 * c + hi) ^ (tl & 7)) << 4);
      sc = MFMA32(*(const bf16x8*)(qr + off), *(const bf16x8*)(kr + off), sc);
    }

    #pragma unroll
    for (int q = 0; q < 4; ++q) {
      f32x4 ad = *(const f32x4*)&adj_sm[h][thalf + 8 * q + 4 * hi];
      #pragma unroll
      for (int r = 0; r < 4; ++r)
        avg[q * 4 + r] += EXP2(sc[q * 4 + r] - ad[r]);
    }

    if (h + 1 < Hn) {
      *(bf16x8*)(qn + ko0) = rq0;
      *(bf16x8*)(qn + ko0 + 4096) = rq1;
      *(bf16x8*)(kn + ko0) = rk0;
      *(bf16x8*)(kn + ko0 + 4096) = rk1;
    }
  }

  #pragma unroll
  for (int q = 0; q < 4; ++q)
    #pragma unroll
    for (int r = 0; r < 4; ++r) {
      int t = tt * 64 + thalf + 8 * q + 4 * hi + r;
      int s = ss * 64 + shalf + tl;
      avg_out[((size_t)(b2 * Tn + t)) * Tn + s] = avg[q * 4 + r];
    }
}

// ---------------------------------------------------------------------------
// Kernel 4: out projection, 128x64 tiles (grid 512 = 2 blocks/CU),
// 2-phase prefetch dbuf gload_lds, fp32 out.
// ---------------------------------------------------------------------------
__global__ __launch_bounds__(256)
void k_outproj(const __bf16* __restrict__ ctx, const __bf16* __restrict__ W,
               const float* __restrict__ bias, float* __restrict__ out)
{
  __shared__ __align__(16) char a_lds[2][8192];  // [4 g][128 r][16B]
  __shared__ __align__(16) char b_lds[2][4096];  // [4 g][64 r][16B]
  const int tid = threadIdx.x;
  const int lane = tid & 63, w = tid >> 6;
  const int ag = lane >> 4, lr = lane & 15;
  const int mBase = blockIdx.x * 128;
  const int oBase = blockIdx.y * 64;

  const int srow = (w & 1) * 64 + lane;
  const int gw = w >> 1;
  const __bf16* paj[2];
  int aD[2];
  #pragma unroll
  for (int j = 0; j < 2; ++j) {
    const int g = 2 * j + gw;
    paj[j] = ctx + (size_t)(mBase + srow) * En + g * 8;
    aD[j] = g * 2048 + (w & 1) * 1024;
  }
  const __bf16* pb = W + (size_t)(oBase + lane) * En + w * 8;
  const int bDst = w * 1024;

  f32x4 acc[2][4];
  #pragma unroll
  for (int i = 0; i < 2; ++i)
    #pragma unroll
    for (int j = 0; j < 4; ++j) { f32x4 z = {0.f,0.f,0.f,0.f}; acc[i][j] = z; }

  #pragma unroll
  for (int j = 0; j < 2; ++j) gload_lds16(paj[j], &a_lds[0][aD[j]]);
  gload_lds16(pb, &b_lds[0][bDst]);
  __syncthreads();

  for (int kt = 0; kt < 32; ++kt) {
    const int cur = kt & 1, nxt = cur ^ 1;
    if (kt + 1 < 32) {
      const int kk = (kt + 1) * 32;
      #pragma unroll
      for (int j = 0; j < 2; ++j) gload_lds16(paj[j] + kk, &a_lds[nxt][aD[j]]);
      gload_lds16(pb + kk, &b_lds[nxt][bDst]);
    }
    bf16x8 af[2], bfr[4];
    #pragma unroll
    for (int mb = 0; mb < 2; ++mb)
      af[mb] = *(const bf16x8*)(&a_lds[cur][ag * 2048 + (w * 32 + mb * 16 + lr) * 16]);
    #pragma unroll
    for (int nb = 0; nb < 4; ++nb)
      bfr[nb] = *(const bf16x8*)(&b_lds[cur][ag * 1024 + (nb * 16 + lr) * 16]);
    #pragma unroll
    for (int mb = 0; mb < 2; ++mb)
      #pragma unroll
      for (int nb = 0; nb < 4; ++nb)
        acc[mb][nb] = MFMA16(af[mb], bfr[nb], acc[mb][nb]);
    __syncthreads();
  }

  #pragma unroll
  for (int nb = 0; nb < 4; ++nb) {
    int o = oBase + nb * 16 + lr;
    float bv = bias[o];
    #pragma unroll
    for (int mb = 0; mb < 2; ++mb)
      #pragma unroll
      for (int r = 0; r < 4; ++r) {
        int i = mBase + w * 32 + mb * 16 + ag * 4 + r;
        out[(size_t)i * En + o] = acc[mb][nb][r] + bv;
      }
  }
}

// ---------------------------------------------------------------------------
extern "C" void kernel_launch(void* const* d_in, const int* in_sizes, int n_in,
                              void* d_out, int out_size, void* d_ws, size_t ws_size,
                              hipStream_t stream)
{
  (void)in_sizes; (void)n_in; (void)out_size; (void)ws_size;
  const float* query = (const float*)d_in[0];
  const float* key   = (const float*)d_in[1];
  const float* value = (const float*)d_in[2];
  const float* in_w  = (const float*)d_in[3];
  const float* in_b  = (const float*)d_in[4];
  const float* out_w = (const float*)d_in[5];
  const float* out_b = (const float*)d_in[6];

  float* attn_out = (float*)d_out;                                 // [T,B,E]
  float* avg_out  = (float*)d_out + (size_t)Tn * Bn * En;          // [B,T,S]

  char* ws = (char*)d_ws;
  const size_t MB = 1u << 20;
  __bf16* q_ws  = (__bf16*)(ws);                    // [B,H,T,D] bf16, 8 MB
  __bf16* k_ws  = (__bf16*)(ws + 8 * MB);           // 8 MB
  __bf16* vt_ws = (__bf16*)(ws + 16 * MB);          // [B,H,D,T] 8 MB
  __bf16* ctx   = (__bf16*)(ws + 24 * MB);          // [T,B,E] 8 MB
  float*  adj_g = (float*)(ws + 32 * MB);           // [B*H][T] 256 KB
  __bf16* w3_bf = (__bf16*)(ws + 33 * MB);          // 6 MB
  __bf16* wo_bf = (__bf16*)(ws + 39 * MB);          // 2 MB

  k_cvtw<<<2048, 256, 0, stream>>>(in_w, out_w, w3_bf, wo_bf);
  k_qkv<<<dim3(32, 24), 256, 0, stream>>>(query, key, value, w3_bf, in_b,
                                          q_ws, k_ws, vt_ws);
  k_flash<<<512, 256, 0, stream>>>(q_ws, k_ws, vt_ws, ctx, adj_g);
  k_avgw<<<2048, 256, 0, stream>>>(q_ws, k_ws, adj_g, avg_out);
  k_outproj<<<dim3(32, 16), 256, 0, stream>>>(ctx, wo_bf, out_b, attn_out);
}

// Round 13
// 204.424 us; speedup vs baseline: 1.0618x; 1.0618x over previous
//
#include <hip/hip_runtime.h>
#include <hip/hip_bf16.h>

typedef float  f32x2  __attribute__((ext_vector_type(2)));
typedef float  f32x4  __attribute__((ext_vector_type(4)));
typedef float  f32x16 __attribute__((ext_vector_type(16)));
typedef __bf16 bf16x8 __attribute__((ext_vector_type(8)));

#define MFMA16(A,B,C) __builtin_amdgcn_mfma_f32_16x16x32_bf16((A),(B),(C),0,0,0)
#define MFMA32(A,B,C) __builtin_amdgcn_mfma_f32_32x32x16_bf16((A),(B),(C),0,0,0)
#define EXP2(x) __builtin_amdgcn_exp2f(x)
#define LOG2(x) __builtin_amdgcn_logf(x)

static constexpr int Tn = 2048, Bn = 2, En = 1024, Hn = 16, Dn = 64;
// Q is pre-scaled by (1/sqrt(D)) * log2(e): all score math is in log2 domain.
static constexpr float kQScale = 0.125f * 1.4426950408889634f;

// XCD-chunked bijective swizzle (T1): valid when nwg % 8 == 0.
static __device__ __forceinline__ int xcd_swz(int bid, int nwg) {
  return (bid & 7) * (nwg >> 3) + (bid >> 3);
}

static __device__ __forceinline__ unsigned pack2(float a, float b) {
  union { __bf16 h[2]; unsigned u; } un;
  un.h[0] = (__bf16)a; un.h[1] = (__bf16)b;
  return un.u;
}

// async global->LDS, 16B per lane; LDS dest is wave-uniform base + lane*16
static __device__ __forceinline__ void gload_lds16(const void* g, void* l) {
  __builtin_amdgcn_global_load_lds(
      (const __attribute__((address_space(1))) void*)g,
      (__attribute__((address_space(3))) void*)l, 16, 0, 0);
}

// ---------------------------------------------------------------------------
// Kernel 0: fp32 -> bf16 convert of Q/K/V inputs and both weight matrices.
// ---------------------------------------------------------------------------
__global__ __launch_bounds__(256)
void k_cvt(const float* __restrict__ q, const float* __restrict__ k,
           const float* __restrict__ v, const float* __restrict__ w3,
           const float* __restrict__ wo,
           __bf16* __restrict__ qb, __bf16* __restrict__ kb,
           __bf16* __restrict__ vb, __bf16* __restrict__ w3b,
           __bf16* __restrict__ wob)
{
  const size_t g = (size_t)blockIdx.x * 256 + threadIdx.x;  // granule id
  const float* src;
  __bf16* dst;
  size_t off;
  if (g < 524288)        { src = q;  dst = qb;  off = g; }
  else if (g < 1048576)  { src = k;  dst = kb;  off = g - 524288; }
  else if (g < 1572864)  { src = v;  dst = vb;  off = g - 1048576; }
  else if (g < 1966080)  { src = w3; dst = w3b; off = g - 1572864; }
  else                   { src = wo; dst = wob; off = g - 1966080; }
  const float* p = src + off * 8;
  f32x4 a = *reinterpret_cast<const f32x4*>(p);
  f32x4 b = *reinterpret_cast<const f32x4*>(p + 4);
  bf16x8 o;
  #pragma unroll
  for (int e = 0; e < 4; ++e) { o[e] = (__bf16)a[e]; o[e + 4] = (__bf16)b[e]; }
  *reinterpret_cast<bf16x8*>(dst + off * 8) = o;
}

// ---------------------------------------------------------------------------
// Kernel 1: fused QKV in-projection, bf16 in, global_load_lds 2-buffer
// prefetch, drain barrier (proven 71 us structure). XCD-chunked swizzle.
// ---------------------------------------------------------------------------
__global__ __launch_bounds__(256)
void k_qkv(const __bf16* __restrict__ Xq, const __bf16* __restrict__ Xk,
           const __bf16* __restrict__ Xv, const __bf16* __restrict__ W,
           const float* __restrict__ bias,
           __bf16* __restrict__ q_ws, __bf16* __restrict__ k_ws,
           __bf16* __restrict__ v_ws)
{
  __shared__ __align__(16) char a_lds[2][8192];
  __shared__ __align__(16) char b_lds[2][8192];
  const int tid = threadIdx.x;
  const int lane = tid & 63, w = tid >> 6;
  const int wr = w >> 1, wc = w & 1;
  const int ag = lane >> 4, lr = lane & 15;
  const int wg = xcd_swz(blockIdx.y * 32 + blockIdx.x, 768);
  const int mBase = (wg & 31) * 128;
  const int by = wg >> 5;
  const int oBase = by * 128;
  const int which = by >> 3;
  const __bf16* X  = (which == 0) ? Xq : ((which == 1) ? Xk : Xv);
  const __bf16* Wt = W + (size_t)oBase * En;
  __bf16* dst = (which == 0) ? q_ws : ((which == 1) ? k_ws : v_ws);
  const float oscale = (which == 0) ? kQScale : 1.0f;

  const int gA = w;                             // wave owns k-granule w
  const __bf16* pa0 = X  + (size_t)(mBase + lane) * En + gA * 8;
  const __bf16* pa1 = X  + (size_t)(mBase + 64 + lane) * En + gA * 8;
  const __bf16* pb0 = Wt + (size_t)(lane) * En + gA * 8;
  const __bf16* pb1 = Wt + (size_t)(64 + lane) * En + gA * 8;

  f32x4 acc[4][4];
  #pragma unroll
  for (int i = 0; i < 4; ++i)
    #pragma unroll
    for (int j = 0; j < 4; ++j) { f32x4 z = {0.f, 0.f, 0.f, 0.f}; acc[i][j] = z; }

  // prologue: stage K-step 0 into buf 0
  gload_lds16(pa0, &a_lds[0][gA * 2048]);
  gload_lds16(pa1, &a_lds[0][gA * 2048 + 1024]);
  gload_lds16(pb0, &b_lds[0][gA * 2048]);
  gload_lds16(pb1, &b_lds[0][gA * 2048 + 1024]);
  __syncthreads();

  for (int kt = 0; kt < 32; ++kt) {
    const int cur = kt & 1, nxt = cur ^ 1;
    if (kt + 1 < 32) {                 // issue next tile BEFORE compute
      const int kk = (kt + 1) * 32;
      gload_lds16(pa0 + kk, &a_lds[nxt][gA * 2048]);
      gload_lds16(pa1 + kk, &a_lds[nxt][gA * 2048 + 1024]);
      gload_lds16(pb0 + kk, &b_lds[nxt][gA * 2048]);
      gload_lds16(pb1 + kk, &b_lds[nxt][gA * 2048 + 1024]);
    }
    bf16x8 af[4], bfr[4];
    #pragma unroll
    for (int mb = 0; mb < 4; ++mb)
      af[mb] = *(const bf16x8*)(&a_lds[cur][ag * 2048 + (wr * 64 + mb * 16 + lr) * 16]);
    #pragma unroll
    for (int nb = 0; nb < 4; ++nb)
      bfr[nb] = *(const bf16x8*)(&b_lds[cur][ag * 2048 + (wc * 64 + nb * 16 + lr) * 16]);
    #pragma unroll
    for (int mb = 0; mb < 4; ++mb)
      #pragma unroll
      for (int nb = 0; nb < 4; ++nb)
        acc[mb][nb] = MFMA16(af[mb], bfr[nb], acc[mb][nb]);
    __syncthreads();                   // drains this iter's glls
  }

  #pragma unroll
  for (int nb = 0; nb < 4; ++nb) {
    int oG = oBase + wc * 64 + nb * 16 + lr;
    float bv = bias[oG];
    int oS = oG & (En - 1);
    int h = oS >> 6, d = oS & 63;
    #pragma unroll
    for (int mb = 0; mb < 4; ++mb)
      #pragma unroll
      for (int r = 0; r < 4; ++r) {
        int i = mBase + wr * 64 + mb * 16 + ag * 4 + r;
        int t = i >> 1, b2 = i & 1;
        dst[(((size_t)(b2 * Hn + h)) * Tn + t) * Dn + d] =
            (__bf16)((acc[mb][nb][r] + bv) * oscale);
      }
  }
}

// ---------------------------------------------------------------------------
// Kernel 1b: V [bh, T, D] -> V^T [bh, D, T]  (bf16), LDS tile transpose.
// ---------------------------------------------------------------------------
__global__ __launch_bounds__(256)
void k_transpose_v(const __bf16* __restrict__ v_ws, __bf16* __restrict__ vt_ws)
{
  __shared__ __bf16 tile[64][72];
  const int bh = blockIdx.x >> 5;
  const int tt = blockIdx.x & 31;
  const int tid = threadIdx.x;
  const __bf16* src = v_ws + ((size_t)bh * Tn + tt * 64) * Dn;
  #pragma unroll
  for (int it = 0; it < 2; ++it) {
    int gi = tid + it * 256;
    int row = gi >> 3, gg = gi & 7;
    *reinterpret_cast<bf16x8*>(&tile[row][gg * 8]) =
        *reinterpret_cast<const bf16x8*>(src + row * Dn + gg * 8);
  }
  __syncthreads();
  __bf16* dst = vt_ws + (size_t)bh * Dn * Tn + tt * 64;
  #pragma unroll
  for (int it = 0; it < 2; ++it) {
    int gi = tid + it * 256;
    int drow = gi >> 3, tg = gi & 7;
    bf16x8 vv;
    #pragma unroll
    for (int e = 0; e < 8; ++e) vv[e] = tile[tg * 8 + e][drow];
    *reinterpret_cast<bf16x8*>(dst + (size_t)drow * Tn + tg * 8) = vv;
  }
}

// ---------------------------------------------------------------------------
// Kernel 2: flash attention (R6-proven 64 us structure) + XCD swizzle.
// Swapped 32x32 MFMA, log2 domain, l via MFMA-vs-ones, permlane32_swap
// P-transpose, defer-max, dbuf K/V (1 barrier/iter), setprio.
// ---------------------------------------------------------------------------
__global__ __launch_bounds__(256, 2)
void k_flash(const __bf16* __restrict__ q_ws, const __bf16* __restrict__ k_ws,
             const __bf16* __restrict__ vt_ws, __bf16* __restrict__ ctx,
             float* __restrict__ adj_g)
{
  __shared__ __align__(16) char kv_sm[2 * 16384];  // [buf][K 8KB | V 8KB]

  const int tid = threadIdx.x;
  const int lane = tid & 63, w = tid >> 6;
  const int tl = lane & 31, hi = lane >> 5;
  const int wg = xcd_swz(blockIdx.x, 512);       // bh-chunks per XCD
  const int bh = wg >> 4;
  const int qt = wg & 15;
  const int t0w = qt * 128 + w * 32;

  const __bf16* kbase  = k_ws + (size_t)bh * Tn * Dn;
  const __bf16* vtbase = vt_ws + (size_t)bh * Dn * Tn;

  bf16x8 qf[4];
  {
    const __bf16* qrow = q_ws + ((size_t)bh * Tn + t0w + tl) * Dn + hi * 8;
    #pragma unroll
    for (int c = 0; c < 4; ++c)
      qf[c] = *reinterpret_cast<const bf16x8*>(qrow + c * 16);
  }

  union { unsigned u[4]; bf16x8 v; } onu;
  #pragma unroll
  for (int j = 0; j < 4; ++j) onu.u[j] = 0x3F803F80u;
  const bf16x8 kOne = onu.v;

  f32x16 accO0, accO1, accL;
  #pragma unroll
  for (int i = 0; i < 16; ++i) { accO0[i] = 0.f; accO1[i] = 0.f; accL[i] = 0.f; }
  float m_run = -INFINITY;

  const int r0 = tid >> 3, s0 = tid & 7;
  const int ldso = ((s0 ^ (r0 & 7)) << 4);
  const int ko0 = r0 * 128 + ldso;              // +4096 => rows 32..63

  bf16x8 rk0 = *(const bf16x8*)(kbase + r0 * 64 + s0 * 8);
  bf16x8 rk1 = *(const bf16x8*)(kbase + (r0 + 32) * 64 + s0 * 8);
  bf16x8 rv0 = *(const bf16x8*)(vtbase + (size_t)r0 * Tn + s0 * 8);
  bf16x8 rv1 = *(const bf16x8*)(vtbase + (size_t)(r0 + 32) * Tn + s0 * 8);
  *(bf16x8*)(kv_sm + ko0) = rk0;
  *(bf16x8*)(kv_sm + ko0 + 4096) = rk1;
  *(bf16x8*)(kv_sm + 8192 + ko0) = rv0;
  *(bf16x8*)(kv_sm + 8192 + ko0 + 4096) = rv1;

  for (int st = 0; st < 32; ++st) {
    __syncthreads();
    const char* cur = kv_sm + (st & 1) * 16384;
    char* nxt = kv_sm + ((st + 1) & 1) * 16384;
    if (st + 1 < 32) {   // issue next tile's loads; land during compute (T14)
      const __bf16* kn = kbase + (size_t)(st + 1) * 64 * Dn;
      const __bf16* vn = vtbase + (st + 1) * 64;
      rk0 = *(const bf16x8*)(kn + r0 * 64 + s0 * 8);
      rk1 = *(const bf16x8*)(kn + (r0 + 32) * 64 + s0 * 8);
      rv0 = *(const bf16x8*)(vn + (size_t)r0 * Tn + s0 * 8);
      rv1 = *(const bf16x8*)(vn + (size_t)(r0 + 32) * Tn + s0 * 8);
    }

    f32x16 sc0, sc1;
    #pragma unroll
    for (int i = 0; i < 16; ++i) { sc0[i] = 0.f; sc1[i] = 0.f; }
    const char* kr0 = cur + tl * 128;
    const char* kr1 = cur + (32 + tl) * 128;
    __builtin_amdgcn_s_setprio(1);
    #pragma unroll
    for (int c = 0; c < 4; ++c) {
      const int off = (((2 * c + hi) ^ (tl & 7)) << 4);
      sc0 = MFMA32(*(const bf16x8*)(kr0 + off), qf[c], sc0);
      sc1 = MFMA32(*(const bf16x8*)(kr1 + off), qf[c], sc1);
    }
    __builtin_amdgcn_s_setprio(0);

    float mx[8];
    #pragma unroll
    for (int i = 0; i < 8; ++i)
      mx[i] = fmaxf(fmaxf(sc0[i], sc0[i + 8]), fmaxf(sc1[i], sc1[i + 8]));
    float tm = fmaxf(fmaxf(fmaxf(mx[0], mx[1]), fmaxf(mx[2], mx[3])),
                     fmaxf(fmaxf(mx[4], mx[5]), fmaxf(mx[6], mx[7])));
    tm = fmaxf(tm, __shfl_xor(tm, 32, 64));
    if (__any(tm > m_run + 8.0f)) {
      const float mn = fmaxf(m_run, tm);
      const float es = EXP2(m_run - mn);   // 0 on first tile
      m_run = mn;
      #pragma unroll
      for (int q = 0; q < 4; ++q)
        #pragma unroll
        for (int rr = 0; rr < 4; ++rr) {
          const float e = __shfl(es, 8 * q + 4 * hi + rr, 32);
          accO0[q * 4 + rr] *= e;
          accO1[q * 4 + rr] *= e;
          accL[q * 4 + rr] *= e;
        }
    }
    #pragma unroll
    for (int i = 0; i < 16; ++i) {
      sc0[i] = EXP2(sc0[i] - m_run);
      sc1[i] = EXP2(sc1[i] - m_run);
    }

    unsigned wA0[4], wB0[4], wA1[4], wB1[4];
    #pragma unroll
    for (int g = 0; g < 4; ++g) {
      wA0[g] = pack2(sc0[4 * g],     sc0[4 * g + 1]);
      wB0[g] = pack2(sc0[4 * g + 2], sc0[4 * g + 3]);
      wA1[g] = pack2(sc1[4 * g],     sc1[4 * g + 1]);
      wB1[g] = pack2(sc1[4 * g + 2], sc1[4 * g + 3]);
    }
    bf16x8 pa[2][2];
    #pragma unroll
    for (int sb = 0; sb < 2; ++sb) {
      const unsigned* WA = sb ? wA1 : wA0;
      const unsigned* WB = sb ? wB1 : wB0;
      #pragma unroll
      for (int c = 0; c < 2; ++c) {
        unsigned w0 = WA[2 * c], w2 = WA[2 * c + 1];
        unsigned w1 = WB[2 * c], w3 = WB[2 * c + 1];
        asm("v_permlane32_swap_b32 %0, %1" : "+v"(w0), "+v"(w2));
        asm("v_permlane32_swap_b32 %0, %1" : "+v"(w1), "+v"(w3));
        union { unsigned u[4]; bf16x8 v; } uu;
        uu.u[0] = w0; uu.u[1] = w1; uu.u[2] = w2; uu.u[3] = w3;
        pa[sb][c] = uu.v;
      }
    }

    const char* vr0 = cur + 8192 + tl * 128;
    const char* vr1 = cur + 8192 + (32 + tl) * 128;
    __builtin_amdgcn_s_setprio(1);
    #pragma unroll
    for (int sb = 0; sb < 2; ++sb)
      #pragma unroll
      for (int c = 0; c < 2; ++c) {
        const int off = (((sb * 4 + c * 2 + hi) ^ (tl & 7)) << 4);
        accO0 = MFMA32(pa[sb][c], *(const bf16x8*)(vr0 + off), accO0);
        accO1 = MFMA32(pa[sb][c], *(const bf16x8*)(vr1 + off), accO1);
        accL  = MFMA32(pa[sb][c], kOne, accL);
      }
    __builtin_amdgcn_s_setprio(0);

    if (st + 1 < 32) {
      *(bf16x8*)(nxt + ko0) = rk0;
      *(bf16x8*)(nxt + ko0 + 4096) = rk1;
      *(bf16x8*)(nxt + 8192 + ko0) = rv0;
      *(bf16x8*)(nxt + 8192 + ko0 + 4096) = rv1;
    }
  }

  const int b2 = bh >> 4, h = bh & 15;
  float adjv[16];
  #pragma unroll
  for (int q = 0; q < 4; ++q)
    #pragma unroll
    for (int rr = 0; rr < 4; ++rr) {
      const int j = q * 4 + rr;
      const float lv = 1.0f / accL[j];
      const int t = t0w + 8 * q + 4 * hi + rr;
      __bf16* cp = ctx + ((size_t)t * Bn + b2) * En + h * 64 + tl;
      cp[0]  = (__bf16)(accO0[j] * lv);
      cp[32] = (__bf16)(accO1[j] * lv);
      const float mrow = __shfl(m_run, 8 * q + 4 * hi + rr, 32);
      adjv[j] = mrow + LOG2(16.0f * accL[j]);
    }
  if (tl == 0) {
    #pragma unroll
    for (int q = 0; q < 4; ++q)
      #pragma unroll
      for (int rr = 0; rr < 4; ++rr) {
        const int t = t0w + 8 * q + 4 * hi + rr;
        adj_g[(size_t)bh * Tn + t] = adjv[q * 4 + rr];
      }
  }
}

// ---------------------------------------------------------------------------
// Kernel 3: avg attention weights (recompute QK^T; adj precomputed by flash).
// Double-buffered Q/K LDS, 1 barrier per head (R6-proven) + XCD swizzle.
// ---------------------------------------------------------------------------
__global__ __launch_bounds__(256)
void k_avgw(const __bf16* __restrict__ q_ws, const __bf16* __restrict__ k_ws,
            const float* __restrict__ adj_g, float* __restrict__ avg_out)
{
  __shared__ __align__(16) char q_sm[2][8192];
  __shared__ __align__(16) char k_sm[2][8192];
  __shared__ __align__(16) float adj_sm[16][64];

  const int tid = threadIdx.x;
  const int lane = tid & 63, w = tid >> 6;
  const int tl = lane & 31, hi = lane >> 5;
  const int wg = xcd_swz(blockIdx.x, 2048);
  const int b2 = wg >> 10;
  const int tt = (wg >> 5) & 31;
  const int ss = wg & 31;
  const int thalf = (w >> 1) * 32, shalf = (w & 1) * 32;

  #pragma unroll
  for (int it = 0; it < 4; ++it) {
    int idx = tid + it * 256;
    int h = idx >> 6, trow = idx & 63;
    adj_sm[h][trow] = adj_g[((size_t)(b2 * Hn + h)) * Tn + tt * 64 + trow];
  }

  const size_t hstride = (size_t)Tn * Dn;
  const __bf16* qb = q_ws + ((size_t)(b2 * Hn) * Tn + tt * 64) * Dn;
  const __bf16* kb = k_ws + ((size_t)(b2 * Hn) * Tn + ss * 64) * Dn;

  const int r0 = tid >> 3, s0 = tid & 7;
  const int ldso = ((s0 ^ (r0 & 7)) << 4);
  const int ko0 = r0 * 128 + ldso;               // +4096 => rows 32..63

  bf16x8 rq0 = *(const bf16x8*)(qb + r0 * 64 + s0 * 8);
  bf16x8 rq1 = *(const bf16x8*)(qb + (r0 + 32) * 64 + s0 * 8);
  bf16x8 rk0 = *(const bf16x8*)(kb + r0 * 64 + s0 * 8);
  bf16x8 rk1 = *(const bf16x8*)(kb + (r0 + 32) * 64 + s0 * 8);
  *(bf16x8*)(q_sm[0] + ko0) = rq0;
  *(bf16x8*)(q_sm[0] + ko0 + 4096) = rq1;
  *(bf16x8*)(k_sm[0] + ko0) = rk0;
  *(bf16x8*)(k_sm[0] + ko0 + 4096) = rk1;

  f32x16 avg;
  #pragma unroll
  for (int i = 0; i < 16; ++i) avg[i] = 0.f;

  for (int h = 0; h < Hn; ++h) {
    __syncthreads();
    const char* qc = q_sm[h & 1];
    const char* kc = k_sm[h & 1];
    char* qn = q_sm[(h + 1) & 1];
    char* kn = k_sm[(h + 1) & 1];
    if (h + 1 < Hn) {
      const __bf16* qp = qb + (size_t)(h + 1) * hstride;
      const __bf16* kp2 = kb + (size_t)(h + 1) * hstride;
      rq0 = *(const bf16x8*)(qp + r0 * 64 + s0 * 8);
      rq1 = *(const bf16x8*)(qp + (r0 + 32) * 64 + s0 * 8);
      rk0 = *(const bf16x8*)(kp2 + r0 * 64 + s0 * 8);
      rk1 = *(const bf16x8*)(kp2 + (r0 + 32) * 64 + s0 * 8);
    }

    f32x16 sc;
    #pragma unroll
    for (int i = 0; i < 16; ++i) sc[i] = 0.f;
    const char* qr = qc + (thalf + tl) * 128;
    const char* kr = kc + (shalf + tl) * 128;
    #pragma unroll
    for (int c = 0; c < 4; ++c) {
      const int off = (((2 * c + hi) ^ (tl & 7)) << 4);
      sc = MFMA32(*(const bf16x8*)(qr + off), *(const bf16x8*)(kr + off), sc);
    }

    #pragma unroll
    for (int q = 0; q < 4; ++q) {
      f32x4 ad = *(const f32x4*)&adj_sm[h][thalf + 8 * q + 4 * hi];
      #pragma unroll
      for (int r = 0; r < 4; ++r)
        avg[q * 4 + r] += EXP2(sc[q * 4 + r] - ad[r]);
    }

    if (h + 1 < Hn) {
      *(bf16x8*)(qn + ko0) = rq0;
      *(bf16x8*)(qn + ko0 + 4096) = rq1;
      *(bf16x8*)(kn + ko0) = rk0;
      *(bf16x8*)(kn + ko0 + 4096) = rk1;
    }
  }

  #pragma unroll
  for (int q = 0; q < 4; ++q)
    #pragma unroll
    for (int r = 0; r < 4; ++r) {
      int t = tt * 64 + thalf + 8 * q + 4 * hi + r;
      int s = ss * 64 + shalf + tl;
      avg_out[((size_t)(b2 * Tn + t)) * Tn + s] = avg[q * 4 + r];
    }
}

// ---------------------------------------------------------------------------
// Kernel 4: out projection, 128x128 tiles (R6-proven), gload_lds 2-buffer
// prefetch, drain barrier, fp32 out.
// ---------------------------------------------------------------------------
__global__ __launch_bounds__(256)
void k_outproj(const __bf16* __restrict__ ctx, const __bf16* __restrict__ W,
               const float* __restrict__ bias, float* __restrict__ out)
{
  __shared__ __align__(16) char a_lds[2][8192];
  __shared__ __align__(16) char b_lds[2][8192];
  const int tid = threadIdx.x;
  const int lane = tid & 63, w = tid >> 6;
  const int wr = w >> 1, wc = w & 1;
  const int ag = lane >> 4, lr = lane & 15;
  const int mBase = blockIdx.x * 128;
  const int oBase = blockIdx.y * 128;
  const __bf16* Wt = W + (size_t)oBase * En;

  const int gA = w;
  const __bf16* pa0 = ctx + (size_t)(mBase + lane) * En + gA * 8;
  const __bf16* pa1 = ctx + (size_t)(mBase + 64 + lane) * En + gA * 8;
  const __bf16* pb0 = Wt + (size_t)(lane) * En + gA * 8;
  const __bf16* pb1 = Wt + (size_t)(64 + lane) * En + gA * 8;

  f32x4 acc[4][4];
  #pragma unroll
  for (int i = 0; i < 4; ++i)
    #pragma unroll
    for (int j = 0; j < 4; ++j) { f32x4 z = {0.f,0.f,0.f,0.f}; acc[i][j] = z; }

  gload_lds16(pa0, &a_lds[0][gA * 2048]);
  gload_lds16(pa1, &a_lds[0][gA * 2048 + 1024]);
  gload_lds16(pb0, &b_lds[0][gA * 2048]);
  gload_lds16(pb1, &b_lds[0][gA * 2048 + 1024]);
  __syncthreads();

  for (int kt = 0; kt < 32; ++kt) {
    const int cur = kt & 1, nxt = cur ^ 1;
    if (kt + 1 < 32) {
      const int kk = (kt + 1) * 32;
      gload_lds16(pa0 + kk, &a_lds[nxt][gA * 2048]);
      gload_lds16(pa1 + kk, &a_lds[nxt][gA * 2048 + 1024]);
      gload_lds16(pb0 + kk, &b_lds[nxt][gA * 2048]);
      gload_lds16(pb1 + kk, &b_lds[nxt][gA * 2048 + 1024]);
    }
    bf16x8 af[4], bfr[4];
    #pragma unroll
    for (int mb = 0; mb < 4; ++mb)
      af[mb] = *(const bf16x8*)(&a_lds[cur][ag * 2048 + (wr * 64 + mb * 16 + lr) * 16]);
    #pragma unroll
    for (int nb = 0; nb < 4; ++nb)
      bfr[nb] = *(const bf16x8*)(&b_lds[cur][ag * 2048 + (wc * 64 + nb * 16 + lr) * 16]);
    #pragma unroll
    for (int mb = 0; mb < 4; ++mb)
      #pragma unroll
      for (int nb = 0; nb < 4; ++nb)
        acc[mb][nb] = MFMA16(af[mb], bfr[nb], acc[mb][nb]);
    __syncthreads();
  }

  #pragma unroll
  for (int nb = 0; nb < 4; ++nb) {
    int o = oBase + wc * 64 + nb * 16 + lr;
    float bv = bias[o];
    #pragma unroll
    for (int mb = 0; mb < 4; ++mb)
      #pragma unroll
      for (int r = 0; r < 4; ++r) {
        int i = mBase + wr * 64 + mb * 16 + ag * 4 + r;
        out[(size_t)i * En + o] = acc[mb][nb][r] + bv;
      }
  }
}

// ---------------------------------------------------------------------------
extern "C" void kernel_launch(void* const* d_in, const int* in_sizes, int n_in,
                              void* d_out, int out_size, void* d_ws, size_t ws_size,
                              hipStream_t stream)
{
  (void)in_sizes; (void)n_in; (void)out_size; (void)ws_size;
  const float* query = (const float*)d_in[0];
  const float* key   = (const float*)d_in[1];
  const float* value = (const float*)d_in[2];
  const float* in_w  = (const float*)d_in[3];
  const float* in_b  = (const float*)d_in[4];
  const float* out_w = (const float*)d_in[5];
  const float* out_b = (const float*)d_in[6];

  float* attn_out = (float*)d_out;                                 // [T,B,E]
  float* avg_out  = (float*)d_out + (size_t)Tn * Bn * En;          // [B,T,S]

  char* ws = (char*)d_ws;
  const size_t MB = 1u << 20;
  __bf16* q_ws  = (__bf16*)(ws);                    // [B,H,T,D] bf16, 8 MB
  __bf16* k_ws  = (__bf16*)(ws + 8 * MB);           // 8 MB
  __bf16* v_ws  = (__bf16*)(ws + 16 * MB);          // 8 MB
  __bf16* vt_ws = (__bf16*)(ws + 24 * MB);          // 8 MB (aliases xq_bf)
  __bf16* ctx   = (__bf16*)(ws + 32 * MB);          // 8 MB (aliases xk_bf)
  float*  adj_g = (float*)(ws + 40 * MB);           // [B*H][T] 256 KB
  __bf16* xq_bf = vt_ws;                            // dead before transpose
  __bf16* xk_bf = ctx;                              // dead before flash
  __bf16* xv_bf = (__bf16*)(ws + 40 * MB + 512 * 1024);   // 8 MB
  __bf16* w3_bf = (__bf16*)(ws + 48 * MB + 512 * 1024);   // 6 MB
  __bf16* wo_bf = (__bf16*)(ws + 54 * MB + 512 * 1024);   // 2 MB

  k_cvt<<<8192, 256, 0, stream>>>(query, key, value, in_w, out_w,
                                  xq_bf, xk_bf, xv_bf, w3_bf, wo_bf);
  k_qkv<<<dim3(32, 24), 256, 0, stream>>>(xq_bf, xk_bf, xv_bf, w3_bf, in_b,
                                          q_ws, k_ws, v_ws);
  k_transpose_v<<<1024, 256, 0, stream>>>(v_ws, vt_ws);
  k_flash<<<512, 256, 0, stream>>>(q_ws, k_ws, vt_ws, ctx, adj_g);
  k_avgw<<<2048, 256, 0, stream>>>(q_ws, k_ws, adj_g, avg_out);
  k_outproj<<<dim3(32, 8), 256, 0, stream>>>(ctx, wo_bf, out_b, attn_out);
}